// Round 6
// baseline (354.912 us; speedup 1.0000x reference)
//
#include <hip/hip_runtime.h>
#include <stdint.h>

#define BLOCK 256   // 128 lane-PAIRS per block; pair = tid>>1, parity p = tid&1
#define PAIRS 128

struct KeySet {
  uint32_t k0L[6], k1L[6], k2L[6], k0R[6], k1R[6], k2R[6];
};

// Threefry-2x32 host copy for the key chain (split) — bit-exact with device.
__host__ inline void tf2x32(uint32_t k0, uint32_t k1, uint32_t x0, uint32_t x1,
                            uint32_t& o0, uint32_t& o1) {
  const uint32_t k2 = k0 ^ k1 ^ 0x1BD11BDAu;
  x0 += k0; x1 += k1;
#define TFR(r) { x0 += x1; x1 = (x1 << (r)) | (x1 >> (32 - (r))); x1 ^= x0; }
  TFR(13) TFR(15) TFR(26) TFR(6)
  x0 += k1; x1 += k2 + 1u;
  TFR(17) TFR(29) TFR(16) TFR(24)
  x0 += k2; x1 += k0 + 2u;
  TFR(13) TFR(15) TFR(26) TFR(6)
  x0 += k0; x1 += k1 + 3u;
  TFR(17) TFR(29) TFR(16) TFR(24)
  x0 += k1; x1 += k2 + 4u;
  TFR(13) TFR(15) TFR(26) TFR(6)
  x0 += k2; x1 += k0 + 5u;
#undef TFR
  o0 = x0; o1 = x1;
}

// Gumbel-softmax weight factor: e^g = 1/(-ln u) ∝ 1/(-log2 u) (ln2 cancels
// in num/den). Weights from LDS are w'_c = exp(logit_c)*2^-24.
__device__ __forceinline__ float wgt(uint32_t bits) {
  const float tiny = 1.17549435e-38f;
  float f = __uint_as_float((bits >> 9) | 0x3f800000u) - 1.0f;
  float u = fmaxf(f, tiny);                 // JAX uniform in [tiny, 1)
  float v = __builtin_amdgcn_logf(u);       // log2(u)
  return __builtin_amdgcn_rcpf(-v);         // neg folds as input modifier
}

__device__ __forceinline__ float expT(float x) {  // sum_{k=0..12} x^k/k!
  float r = 2.0876756987868099e-9f;               // 1/12!
  r = fmaf(r, x, 2.5052108385441719e-8f);
  r = fmaf(r, x, 2.7557319223985893e-7f);
  r = fmaf(r, x, 2.7557319223985888e-6f);
  r = fmaf(r, x, 2.4801587301587302e-5f);
  r = fmaf(r, x, 1.9841269841269841e-4f);
  r = fmaf(r, x, 1.3888888888888889e-3f);
  r = fmaf(r, x, 8.3333333333333332e-3f);
  r = fmaf(r, x, 4.1666666666666664e-2f);
  r = fmaf(r, x, 1.6666666666666666e-1f);
  r = fmaf(r, x, 0.5f);
  r = fmaf(r, x, 1.0f);
  r = fmaf(r, x, 1.0f);
  return r;
}

__device__ __forceinline__ float lnT(float y) {   // k=16..1: r = 1/k - z*r; z*r
  const float inv[15] = {1.0f/15.0f, 1.0f/14.0f, 1.0f/13.0f, 1.0f/12.0f,
                         1.0f/11.0f, 0.1f, 1.0f/9.0f, 0.125f, 1.0f/7.0f, 1.0f/6.0f,
                         0.2f, 0.25f, 1.0f/3.0f, 0.5f, 1.0f};
  float z = y - 1.0f;
  float r = 1.0f/16.0f;                     // first iteration folded
#pragma unroll
  for (int i = 0; i < 15; ++i) r = fmaf(-z, r, inv[i]);
  return z * r;
}

// One node, ONE side per lane (even=L, odd=R): C threefry chains, softmax
// dot, clamp, then the parity-appropriate half of eml; combine with the
// partner lane via shfl_xor. Accumulation order identical to R5 per side.
// w8p = wz + node*16 + p*8 (parity-offset); keys/xb parity-selected.
template<int C>
__device__ __forceinline__ float node_pair(
    const float* __restrict__ w8p,
    uint32_t k0, uint32_t k1, uint32_t k2,
    uint32_t xb,                     // bt*stride + k1_sel + n*C
    float4 xv, float pc, uint32_t p) {
  uint32_t a0[C], a1[C];
#pragma unroll
  for (int i = 0; i < C; ++i) { a0[i] = k0; a1[i] = xb + (uint32_t)i; }
#define HALF(r) \
  _Pragma("unroll") for (int i = 0; i < C; ++i) { \
    a0[i] += a1[i]; \
    a1[i] = __builtin_rotateleft32(a1[i], (r)); \
    a1[i] ^= a0[i]; }
#define INJ(A, B, add) \
  _Pragma("unroll") for (int i = 0; i < C; ++i) { a0[i] += (A); a1[i] += (B) + (add); }
  HALF(13) HALF(15) HALF(26) HALF(6)
  INJ(k1, k2, 1u)
  HALF(17) HALF(29) HALF(16) HALF(24)
  INJ(k2, k0, 2u)
  HALF(13) HALF(15) HALF(26) HALF(6)
  INJ(k0, k1, 3u)
  HALF(17) HALF(29) HALF(16) HALF(24)
  INJ(k1, k2, 4u)
  HALF(13) HALF(15) HALF(26) HALF(6)
#undef HALF
#undef INJ
  float wv[C];
#pragma unroll
  for (int i = 0; i < C; ++i) wv[i] = wgt((a0[i] + k2) ^ (a1[i] + (k0 + 5u)));
  float4 wa = *reinterpret_cast<const float4*>(w8p);
  float e = wa.x * wv[0];
  float den = e, num = e;
  e = wa.y * wv[1]; den += e; num = fmaf(e, xv.x, num);
  e = wa.z * wv[2]; den += e; num = fmaf(e, xv.y, num);
  e = wa.w * wv[3]; den += e; num = fmaf(e, xv.z, num);
  e = w8p[4] * wv[4]; den += e; num = fmaf(e, xv.w, num);
  if constexpr (C == 6) { e = w8p[5] * wv[5]; den += e; num = fmaf(e, pc, num); }
  float val = num * __builtin_amdgcn_rcpf(den);
  float vx = __builtin_amdgcn_fmed3f(val, -5.0f, 5.0f);  // CLAMP   (L lane)
  float vy = fmaxf(val, 1e-30f);                          // LN_EPS  (R lane)
  float v = p ? vy : vx;
  // Both polys, predicated select (no divergence). Discarded path may be
  // inf (expT of huge ey) — select kills it, never blended arithmetically.
  float pe = expT(v);
  float pl = lnT(v);
  float part = p ? pl : pe;
  return part + __shfl_xor(part, 1);    // both lanes get expT(ex)+lnT(ey)
}

// Stage one level's logits into padded weight layout [node][side][8]:
// w' = exp2(logit*log2e - 24)  (2^-24 prevents num overflow when rcp
// weights (<=5.8e6) meet prev ~ 1e33).
template<int C>
__device__ __forceinline__ void stage(const float* __restrict__ g, float* __restrict__ ws,
                                      int t, int N, int woff, int tid) {
  const int total = N * C * 2;
  const float* src = g + t * total;
  for (int i = tid; i < total; i += BLOCK) {
    int n = i / (2 * C);
    int rem = i - n * 2 * C;
    int c = rem >> 1, s = rem & 1;
    ws[woff + n * 16 + s * 8 + c] =
        __builtin_amdgcn_exp2f(fmaf(src[i], 1.4426950408889634f, -24.0f));
  }
}

__global__ __launch_bounds__(BLOCK, 8) void eml_kernel(
    const float* __restrict__ x,
    const float* __restrict__ g0, const float* __restrict__ g1,
    const float* __restrict__ g2, const float* __restrict__ g3,
    const float* __restrict__ g4, const float* __restrict__ g5,
    float* __restrict__ out, KeySet ks) {
  __shared__ float wz[1008];            // padded weights, levels concatenated
  __shared__ float pvs[16 * PAIRS];     // l1 outputs [node][pair]
  const int tid = threadIdx.x;
  const int t = blockIdx.x & 127;
  const int chunk = blockIdx.x >> 7;    // 0..15

  stage<5>(g0, wz, t, 32,   0, tid);
  stage<6>(g1, wz, t, 16, 512, tid);
  stage<6>(g2, wz, t,  8, 768, tid);
  stage<6>(g3, wz, t,  4, 896, tid);
  stage<6>(g4, wz, t,  2, 960, tid);
  stage<6>(g5, wz, t,  1, 992, tid);
  __syncthreads();

  const int pair = tid >> 1;
  const uint32_t p = (uint32_t)(tid & 1);            // 0 = L side, 1 = R side
  const int b = chunk * PAIRS + pair;                // 0..2047
  const uint32_t bt = (uint32_t)(b * 128 + t);       // flat (b,t) index
  const float4 xv = reinterpret_cast<const float4*>(x)[b];
  float* pv = &pvs[pair];
  const int p8 = (int)(p * 8u);                      // weight parity offset

  // Parity-selected keys + counter bases per level (k1 pre-added).
  uint32_t K0[6], K1[6], K2[6], XB[6];
  const uint32_t strides[6] = {160u, 96u, 48u, 24u, 12u, 6u};
#pragma unroll
  for (int l = 0; l < 6; ++l) {
    K0[l] = p ? ks.k0R[l] : ks.k0L[l];
    K1[l] = p ? ks.k1R[l] : ks.k1L[l];
    K2[l] = p ? ks.k2R[l] : ks.k2L[l];
    XB[l] = bt * strides[l] + K1[l];
  }

  // L0 + L1 fused: l0 nodes (2n, 2n+1) feed l1 node n through registers.
  for (int n = 0; n < 16; ++n) {
    const uint32_t o = (uint32_t)(10 * n);   // l0 node 2n -> choice offset 5*(2n)
    float rl = node_pair<5>(wz + (2 * n) * 16 + p8, K0[0], K1[0], K2[0],
                            XB[0] + o, xv, 0.0f, p);
    float rr = node_pair<5>(wz + (2 * n + 1) * 16 + p8, K0[0], K1[0], K2[0],
                            XB[0] + o + 5u, xv, 0.0f, p);
    float pc = p ? rr : rl;                  // L lane gets prev[2n], R gets prev[2n+1]
    float rn = node_pair<6>(wz + 512 + n * 16 + p8, K0[1], K1[1], K2[1],
                            XB[1] + (uint32_t)(6 * n), xv, pc, p);
    if (!p) pv[n * PAIRS] = rn;              // intra-wave LDS; no barrier needed
  }
  // L2 + L3 fused. Reads rows 4n+{0..3}; write row n after (hazard-free).
  for (int n = 0; n < 4; ++n) {
    const uint32_t o = (uint32_t)(12 * n);   // l2 node 2n -> choice offset 6*(2n)
    float pcA = pv[(4 * n + (int)p) * PAIRS];        // L: row 4n,   R: row 4n+1
    float pcB = pv[(4 * n + 2 + (int)p) * PAIRS];    // L: row 4n+2, R: row 4n+3
    float rl = node_pair<6>(wz + 768 + (2 * n) * 16 + p8, K0[2], K1[2], K2[2],
                            XB[2] + o, xv, pcA, p);
    float rr = node_pair<6>(wz + 768 + (2 * n + 1) * 16 + p8, K0[2], K1[2], K2[2],
                            XB[2] + o + 6u, xv, pcB, p);
    float pc = p ? rr : rl;
    float rn = node_pair<6>(wz + 896 + n * 16 + p8, K0[3], K1[3], K2[3],
                            XB[3] + (uint32_t)(6 * n), xv, pc, p);
    if (!p) pv[n * PAIRS] = rn;
  }
  // L4 + L5 fused; final result straight to global.
  {
    float pcA = pv[((int)p) * PAIRS];        // L: row 0, R: row 1
    float pcB = pv[(2 + (int)p) * PAIRS];    // L: row 2, R: row 3
    float rl = node_pair<6>(wz + 960 + p8, K0[4], K1[4], K2[4],
                            XB[4], xv, pcA, p);
    float rr = node_pair<6>(wz + 960 + 16 + p8, K0[4], K1[4], K2[4],
                            XB[4] + 6u, xv, pcB, p);
    float pc = p ? rr : rl;
    float rf = node_pair<6>(wz + 992 + p8, K0[5], K1[5], K2[5],
                            XB[5], xv, pc, p);
    if (!p) out[bt] = rf;
  }
}

extern "C" void kernel_launch(void* const* d_in, const int* in_sizes, int n_in,
                              void* d_out, int out_size, void* d_ws, size_t ws_size,
                              hipStream_t stream) {
  const float* x  = (const float*)d_in[0];
  const float* g0 = (const float*)d_in[1];
  const float* g1 = (const float*)d_in[2];
  const float* g2 = (const float*)d_in[3];
  const float* g3 = (const float*)d_in[4];
  const float* g4 = (const float*)d_in[5];
  const float* g5 = (const float*)d_in[6];
  float* out = (float*)d_out;

  // Key chain: key(42) = (0,42); per level split(key,3) fold-like:
  // key' = tf(key,(0,0)), kL = tf(key,(0,1)), kR = tf(key,(0,2)).
  KeySet ks;
  uint32_t K0 = 0u, K1 = 42u;
  for (int l = 0; l < 6; ++l) {
    uint32_t n0, n1, a0, a1, c0, c1;
    tf2x32(K0, K1, 0u, 0u, n0, n1);
    tf2x32(K0, K1, 0u, 1u, a0, a1);
    tf2x32(K0, K1, 0u, 2u, c0, c1);
    ks.k0L[l] = a0; ks.k1L[l] = a1; ks.k2L[l] = a0 ^ a1 ^ 0x1BD11BDAu;
    ks.k0R[l] = c0; ks.k1R[l] = c1; ks.k2R[l] = c0 ^ c1 ^ 0x1BD11BDAu;
    K0 = n0; K1 = n1;
  }

  eml_kernel<<<dim3(2048), dim3(BLOCK), 0, stream>>>(x, g0, g1, g2, g3, g4, g5, out, ks);
}